// Round 1
// baseline (18014.819 us; speedup 1.0000x reference)
//
#include <hip/hip_runtime.h>
#include <hip/hip_bf16.h>
#include <math.h>

// Problem constants
#define BB 32     // batch
#define TT 128    // encoder timesteps
#define HH 512    // hidden
#define VV 32000  // vocab
#define SS 64     // decode steps (BLOCK)

__device__ __forceinline__ float tanh_fast(float x) {
    // tanh(x) = 1 - 2/(exp(2x)+1); graceful at +-inf
    return 1.f - 2.f / (__expf(2.f * x) + 1.f);
}
__device__ __forceinline__ float sigmoid_fast(float x) {
    return 1.f / (1.f + __expf(-x));
}

// ---------------------------------------------------------------------------
// Gather teacher-forced embeddings: emb_seq[r=b*64+s, :] = embedding[inputs_seq[b,s]]
// inputs_seq[b,0]=BOS(=1); inputs_seq[b,s]=target[b,s-1]
// grid 2048 blocks x 256 threads
__global__ void gather_emb(const int* __restrict__ tgt,
                           const float* __restrict__ emb,
                           float* __restrict__ out) {
    int r = blockIdx.x;
    int b = r >> 6, s = r & 63;
    int id = (s == 0) ? 1 : tgt[b * SS + (s - 1)];
    const float* ep = emb + (size_t)id * HH;
    float* op = out + (size_t)r * HH;
    op[threadIdx.x] = ep[threadIdx.x];
    op[threadIdx.x + 256] = ep[threadIdx.x + 256];
}

// ---------------------------------------------------------------------------
// Generic fp32 GEMM: C[M,N] = A[M,K] @ B[N,K]^T + bias[N]
// 64x64 tile, BK=16, 256 threads, 4x4 per thread. Dims must divide tiles (they do).
// grid (N/64, M/64)
__global__ __launch_bounds__(256) void gemm_bias(
    const float* __restrict__ A, int lda,
    const float* __restrict__ Bm, int ldb,
    const float* __restrict__ bias,
    float* __restrict__ C, int ldc, int K) {
    __shared__ float As[16][65];
    __shared__ float Bs[16][65];
    int tid = threadIdx.x;
    int tx = tid & 15, ty = tid >> 4;
    int m0 = blockIdx.y * 64, n0 = blockIdx.x * 64;
    float acc[4][4] = {};
    for (int k0 = 0; k0 < K; k0 += 16) {
#pragma unroll
        for (int i = 0; i < 4; i++) {
            int idx = tid + i * 256;
            int r = idx >> 4, kk = idx & 15;
            As[kk][r] = A[(size_t)(m0 + r) * lda + k0 + kk];
            Bs[kk][r] = Bm[(size_t)(n0 + r) * ldb + k0 + kk];
        }
        __syncthreads();
#pragma unroll
        for (int kk = 0; kk < 16; kk++) {
            float a[4], bv[4];
#pragma unroll
            for (int i = 0; i < 4; i++) a[i] = As[kk][ty * 4 + i];
#pragma unroll
            for (int j = 0; j < 4; j++) bv[j] = Bs[kk][tx * 4 + j];
#pragma unroll
            for (int i = 0; i < 4; i++)
#pragma unroll
                for (int j = 0; j < 4; j++) acc[i][j] += a[i] * bv[j];
        }
        __syncthreads();
    }
#pragma unroll
    for (int i = 0; i < 4; i++) {
        int m = m0 + ty * 4 + i;
#pragma unroll
        for (int j = 0; j < 4; j++) {
            int n = n0 + tx * 4 + j;
            C[(size_t)m * ldc + n] = acc[i][j] + bias[n];
        }
    }
}

// ---------------------------------------------------------------------------
// Sequential recurrence: one block per batch element, 64 steps in-kernel.
// Attention (q, scores, softmax, ctx) + GRU cell. h lives in LDS.
// Uses precomputed ua_keys and Gi_e (embedding half of GRU input gates).
__global__ __launch_bounds__(1024) void recur_kernel(
    const float* __restrict__ enc,      // [B,T,H]
    const float* __restrict__ enc_hid,  // [1,B,H]
    const float* __restrict__ Wa_w, const float* __restrict__ Wa_b,
    const float* __restrict__ Va_w, const float* __restrict__ Va_b,
    const float* __restrict__ W_ih,     // [3H, 2H]
    const float* __restrict__ W_hh,     // [3H, H]
    const float* __restrict__ b_hh,
    const float* __restrict__ ua,       // [B,T,H]
    const float* __restrict__ gie,      // [B*S, 3H]  (includes b_ih)
    float* __restrict__ hs,             // [B*S, H]
    float* __restrict__ out_hT,         // [B,H]
    float* __restrict__ out_attn) {     // [B,S,T]
    int b = blockIdx.x;
    int tid = threadIdx.x;
    __shared__ float sh_h[HH], sh_q[HH], sh_sc[TT], sh_w[TT], sh_ctx[HH];
    __shared__ float sh_A[2 * HH], sh_gin[HH], sh_ghn[HH];

    if (tid < HH) sh_h[tid] = enc_hid[b * HH + tid];
    __syncthreads();

    for (int s = 0; s < SS; s++) {
        // ---- q = h @ Wa_w^T + Wa_b  (thread per output row)
        if (tid < HH) {
            const float* wr = Wa_w + (size_t)tid * HH;
            float acc = Wa_b[tid];
#pragma unroll 8
            for (int k = 0; k < HH; k++) acc += wr[k] * sh_h[k];
            sh_q[tid] = acc;
        }
        __syncthreads();
        // ---- scores[t] = sum_o tanh(q[o]+ua[b,t,o]) * Va_w[o] + Va_b
        {
            int t = tid >> 3, sub = tid & 7;
            const float* uap = ua + ((size_t)(b * TT + t)) * HH;
            float acc = 0.f;
            for (int o = sub; o < HH; o += 8)
                acc += tanh_fast(sh_q[o] + uap[o]) * Va_w[o];
            acc += __shfl_down(acc, 4, 8);
            acc += __shfl_down(acc, 2, 8);
            acc += __shfl_down(acc, 1, 8);
            if (sub == 0) sh_sc[t] = acc + Va_b[0];
        }
        __syncthreads();
        // ---- softmax over T=128 in one wave; also emit attentions
        if (tid < 64) {
            float a = sh_sc[tid], c = sh_sc[tid + 64];
            float m = fmaxf(a, c);
            for (int off = 32; off; off >>= 1) m = fmaxf(m, __shfl_xor(m, off));
            float ea = __expf(a - m), ec = __expf(c - m);
            float ssum = ea + ec;
            for (int off = 32; off; off >>= 1) ssum += __shfl_xor(ssum, off);
            float inv = 1.f / ssum;
            float wa = ea * inv, wc = ec * inv;
            sh_w[tid] = wa;
            sh_w[tid + 64] = wc;
            float* ap = out_attn + ((size_t)(b * SS + s)) * TT;
            ap[tid] = wa;
            ap[tid + 64] = wc;
        }
        __syncthreads();
        // ---- ctx[h] = sum_t w[t] * enc[b,t,h]
        if (tid < HH) {
            const float* ep = enc + ((size_t)b * TT) * HH + tid;
            float acc = 0.f;
#pragma unroll 4
            for (int t2 = 0; t2 < TT; t2++) acc += sh_w[t2] * ep[t2 * HH];
            sh_ctx[tid] = acc;
        }
        __syncthreads();
        // ---- gates: gi[j] = Gi_e[b,s,j] + W_ih[j,512:]·ctx ; gh[j] = W_hh[j,:]·h + b_hh
        const float* giep = gie + ((size_t)(b * SS + s)) * (3 * HH);
        for (int j = tid; j < 3 * HH; j += 1024) {
            const float* wc_r = W_ih + (size_t)j * (2 * HH) + HH;
            const float* wh_r = W_hh + (size_t)j * HH;
            float gc = 0.f, gh = b_hh[j];
#pragma unroll 8
            for (int k = 0; k < HH; k++) {
                gc += wc_r[k] * sh_ctx[k];
                gh += wh_r[k] * sh_h[k];
            }
            float gi = giep[j] + gc;
            if (j < 2 * HH) sh_A[j] = gi + gh;       // r,z pre-activations
            else { sh_gin[j - 2 * HH] = gi; sh_ghn[j - 2 * HH] = gh; }
        }
        __syncthreads();
        // ---- gate nonlinearities + h update
        if (tid < HH) {
            float r = sigmoid_fast(sh_A[tid]);
            float z = sigmoid_fast(sh_A[HH + tid]);
            float n = tanh_fast(sh_gin[tid] + r * sh_ghn[tid]);
            float hn = (1.f - z) * n + z * sh_h[tid];
            sh_h[tid] = hn;
            hs[((size_t)(b * SS + s)) * HH + tid] = hn;
        }
        __syncthreads();
    }
    if (tid < HH) out_hT[b * HH + tid] = sh_h[tid];
}

// ---------------------------------------------------------------------------
// In-place log_softmax over rows of 32000. One block per row.
__global__ __launch_bounds__(256) void lse_kernel(float* __restrict__ logits) {
    int row = blockIdx.x;
    float* rp = logits + (size_t)row * VV;
    int tid = threadIdx.x;
    __shared__ float red[4];
    __shared__ float bc;
    float m = -INFINITY;
    for (int i = tid; i < VV; i += 256) m = fmaxf(m, rp[i]);
    for (int off = 32; off; off >>= 1) m = fmaxf(m, __shfl_xor(m, off));
    if ((tid & 63) == 0) red[tid >> 6] = m;
    __syncthreads();
    if (tid == 0) bc = fmaxf(fmaxf(red[0], red[1]), fmaxf(red[2], red[3]));
    __syncthreads();
    m = bc;
    float ssum = 0.f;
    for (int i = tid; i < VV; i += 256) ssum += __expf(rp[i] - m);
    for (int off = 32; off; off >>= 1) ssum += __shfl_xor(ssum, off);
    if ((tid & 63) == 0) red[tid >> 6] = ssum;
    __syncthreads();
    if (tid == 0) bc = m + logf(red[0] + red[1] + red[2] + red[3]);
    __syncthreads();
    float lse = bc;
    for (int i = tid; i < VV; i += 256) rp[i] -= lse;
}

// ---------------------------------------------------------------------------
extern "C" void kernel_launch(void* const* d_in, const int* in_sizes, int n_in,
                              void* d_out, int out_size, void* d_ws, size_t ws_size,
                              hipStream_t stream) {
    const float* enc     = (const float*)d_in[0];
    const float* enc_hid = (const float*)d_in[1];
    const int*   tgt     = (const int*)d_in[2];
    const float* emb     = (const float*)d_in[3];
    const float* Wa_w    = (const float*)d_in[4];
    const float* Wa_b    = (const float*)d_in[5];
    const float* Ua_w    = (const float*)d_in[6];
    const float* Ua_b    = (const float*)d_in[7];
    const float* Va_w    = (const float*)d_in[8];
    const float* Va_b    = (const float*)d_in[9];
    const float* W_ih    = (const float*)d_in[10];
    const float* W_hh    = (const float*)d_in[11];
    const float* b_ih    = (const float*)d_in[12];
    const float* b_hh    = (const float*)d_in[13];
    const float* out_w   = (const float*)d_in[14];
    const float* out_b   = (const float*)d_in[15];
    float* out = (float*)d_out;

    float* ws      = (float*)d_ws;
    float* ws_emb  = ws;                          // 2048*512   =  1,048,576
    float* ws_ua   = ws_emb + 2048 * 512;         // 4096*512   =  2,097,152
    float* ws_gie  = ws_ua + 4096 * 512;          // 2048*1536  =  3,145,728
    float* ws_hs   = ws_gie + 2048 * 1536;        // 2048*512   =  1,048,576

    float* out_logits = out;                                  // [B*S, V]
    float* out_hT     = out + (size_t)BB * SS * VV;           // [B, H]
    float* out_attn   = out_hT + (size_t)BB * HH;             // [B, S, T]

    // Teacher-forced embedding gather
    gather_emb<<<dim3(2048), dim3(256), 0, stream>>>(tgt, emb, ws_emb);
    // ua_keys = enc @ Ua_w^T + Ua_b   [4096, 512]
    gemm_bias<<<dim3(8, 64), dim3(256), 0, stream>>>(
        enc, HH, Ua_w, HH, Ua_b, ws_ua, HH, HH);
    // Gi_e = emb_seq @ W_ih[:, :512]^T + b_ih   [2048, 1536]
    gemm_bias<<<dim3(24, 32), dim3(256), 0, stream>>>(
        ws_emb, HH, W_ih, 2 * HH, b_ih, ws_gie, 3 * HH, HH);
    // Sequential attention+GRU recurrence (stores all h_s)
    recur_kernel<<<dim3(BB), dim3(1024), 0, stream>>>(
        enc, enc_hid, Wa_w, Wa_b, Va_w, Va_b, W_ih, W_hh, b_hh,
        ws_ua, ws_gie, ws_hs, out_hT, out_attn);
    // logits = Hs @ out_w^T + out_b   [2048, 32000]
    gemm_bias<<<dim3(500, 32), dim3(256), 0, stream>>>(
        ws_hs, HH, out_w, HH, out_b, out_logits, VV, HH);
    // in-place log_softmax per row
    lse_kernel<<<dim3(2048), dim3(256), 0, stream>>>(out_logits);
}

// Round 2
// 8973.552 us; speedup vs baseline: 2.0075x; 2.0075x over previous
//
#include <hip/hip_runtime.h>
#include <hip/hip_bf16.h>
#include <math.h>

// Problem constants
#define BB 32     // batch
#define TT 128    // encoder timesteps
#define HH 512    // hidden
#define VV 32000  // vocab
#define SS 64     // decode steps (BLOCK)
#define NSL 8     // slices (blocks) per batch element

__device__ __forceinline__ float tanh_fast(float x) {
    return 1.f - 2.f / (__expf(2.f * x) + 1.f);
}
__device__ __forceinline__ float sigmoid_fast(float x) {
    return 1.f / (1.f + __expf(-x));
}

// ---------------------------------------------------------------------------
// Gather teacher-forced embeddings
__global__ void gather_emb(const int* __restrict__ tgt,
                           const float* __restrict__ emb,
                           float* __restrict__ out) {
    int r = blockIdx.x;
    int b = r >> 6, s = r & 63;
    int id = (s == 0) ? 1 : tgt[b * SS + (s - 1)];
    const float* ep = emb + (size_t)id * HH;
    float* op = out + (size_t)r * HH;
    op[threadIdx.x] = ep[threadIdx.x];
    op[threadIdx.x + 256] = ep[threadIdx.x + 256];
}

// ---------------------------------------------------------------------------
// Generic fp32 GEMM: C[M,N] = A[M,K] @ B[N,K]^T + bias[N]
__global__ __launch_bounds__(256) void gemm_bias(
    const float* __restrict__ A, int lda,
    const float* __restrict__ Bm, int ldb,
    const float* __restrict__ bias,
    float* __restrict__ C, int ldc, int K) {
    __shared__ float As[16][65];
    __shared__ float Bs[16][65];
    int tid = threadIdx.x;
    int tx = tid & 15, ty = tid >> 4;
    int m0 = blockIdx.y * 64, n0 = blockIdx.x * 64;
    float acc[4][4] = {};
    for (int k0 = 0; k0 < K; k0 += 16) {
#pragma unroll
        for (int i = 0; i < 4; i++) {
            int idx = tid + i * 256;
            int r = idx >> 4, kk = idx & 15;
            As[kk][r] = A[(size_t)(m0 + r) * lda + k0 + kk];
            Bs[kk][r] = Bm[(size_t)(n0 + r) * ldb + k0 + kk];
        }
        __syncthreads();
#pragma unroll
        for (int kk = 0; kk < 16; kk++) {
            float a[4], bv[4];
#pragma unroll
            for (int i = 0; i < 4; i++) a[i] = As[kk][ty * 4 + i];
#pragma unroll
            for (int j = 0; j < 4; j++) bv[j] = Bs[kk][tx * 4 + j];
#pragma unroll
            for (int i = 0; i < 4; i++)
#pragma unroll
                for (int j = 0; j < 4; j++) acc[i][j] += a[i] * bv[j];
        }
        __syncthreads();
    }
#pragma unroll
    for (int i = 0; i < 4; i++) {
        int m = m0 + ty * 4 + i;
#pragma unroll
        for (int j = 0; j < 4; j++) {
            int n = n0 + tx * 4 + j;
            C[(size_t)m * ldc + n] = acc[i][j] + bias[n];
        }
    }
}

// ---------------------------------------------------------------------------
// Cross-block generation barrier for an 8-block group (monotonic counter).
__device__ __forceinline__ void group_bar(int* ctr, int target) {
    __syncthreads();
    if (threadIdx.x == 0) {
        __hip_atomic_fetch_add(ctr, 1, __ATOMIC_RELEASE, __HIP_MEMORY_SCOPE_AGENT);
        while (__hip_atomic_load(ctr, __ATOMIC_RELAXED, __HIP_MEMORY_SCOPE_AGENT) < target)
            __builtin_amdgcn_s_sleep(1);
        __builtin_amdgcn_fence(__ATOMIC_ACQUIRE, "agent");
    }
    __syncthreads();
}

// ---------------------------------------------------------------------------
// Distributed recurrence: 256 blocks = 32 batch x 8 slices, 256 threads.
// Slice sl of batch b owns h/ctx/q indices [64*sl, 64*sl+64) and k-slices the
// gate GEMV so ctx never needs publishing.
__global__ __launch_bounds__(256) void recur2(
    const float* __restrict__ enc,      // [B,T,H]
    const float* __restrict__ enc_hid,  // [1,B,H]
    const float* __restrict__ Wa_w, const float* __restrict__ Wa_b,
    const float* __restrict__ Va_w, const float* __restrict__ Va_b,
    const float* __restrict__ W_ih,     // [3H, 2H]
    const float* __restrict__ W_hh,     // [3H, H]
    const float* __restrict__ b_hh,
    const float* __restrict__ ua,       // [B,T,H]
    const float* __restrict__ gie,      // [B*S, 3H] (includes b_ih)
    int* __restrict__ sync,             // [B] zeroed counters
    float* __restrict__ scp,            // [NSL][B][TT] score partials
    float* __restrict__ gp,             // [NSL][B][2048] gate partials
    float* __restrict__ hs,             // [B*S, H] all hidden states
    float* __restrict__ out_hT,         // [B,H]
    float* __restrict__ out_attn) {     // [B,S,T]
    int blk = blockIdx.x;
    int b = blk >> 3, sl = blk & 7;
    int tid = threadIdx.x;
    int w = tid >> 6, lane = tid & 63;

    __shared__ __align__(16) float sh_h[HH];
    __shared__ __align__(16) float sh_q[64];
    __shared__ __align__(16) float sh_ctx[64];
    __shared__ float sh_sc[TT], sh_w[TT];
    __shared__ float sh_cp[4][64];

    int* ctr = sync + b;
    int bc = 0;
    float* scp_b = scp + (size_t)(sl * BB + b) * TT;
    float* gp_b  = gp  + (size_t)(sl * BB + b) * 2048;

    for (int s = 0; s < SS; s++) {
        // ---- load full h (previous step's, or encoder hidden at s=0)
        const float* hsrc = (s == 0) ? (enc_hid + b * HH)
                                     : (hs + ((size_t)(b * SS + s - 1)) * HH);
        sh_h[tid] = hsrc[tid];
        sh_h[tid + 256] = hsrc[tid + 256];
        __syncthreads();

        // ---- Phase 1: my 64 q rows (wave-per-row, float4 coalesced)
        {
            const float4* h4 = (const float4*)sh_h;
            float4 h0 = h4[lane], h1 = h4[64 + lane];
            for (int r = 0; r < 16; r++) {
                int o = 64 * sl + w * 16 + r;
                const float4* wp = (const float4*)(Wa_w + (size_t)o * HH);
                float4 a0 = wp[lane], a1 = wp[64 + lane];
                float acc = a0.x * h0.x + a0.y * h0.y + a0.z * h0.z + a0.w * h0.w
                          + a1.x * h1.x + a1.y * h1.y + a1.z * h1.z + a1.w * h1.w;
#pragma unroll
                for (int off = 32; off; off >>= 1) acc += __shfl_xor(acc, off);
                if (lane == 0) sh_q[w * 16 + r] = acc + Wa_b[o];
            }
        }
        __syncthreads();

        // ---- Phase 2: partial scores over my o-range, all 128 t
        {
            float va = Va_w[64 * sl + lane];
            float myq = sh_q[lane];
            const float* uab = ua + ((size_t)b * TT + w * 32) * HH + 64 * sl + lane;
            for (int tt = 0; tt < 32; tt++) {
                float x = tanh_fast(myq + uab[(size_t)tt * HH]) * va;
#pragma unroll
                for (int off = 32; off; off >>= 1) x += __shfl_xor(x, off);
                if (lane == 0) scp_b[w * 32 + tt] = x;
            }
        }
        bc += NSL; group_bar(ctr, bc);   // scores published

        // ---- Phase 3: redundant softmax (cheap), slice 0 emits attention
        if (tid < TT) {
            float sc = Va_b[0];
#pragma unroll
            for (int s2 = 0; s2 < NSL; s2++) sc += scp[(size_t)(s2 * BB + b) * TT + tid];
            sh_sc[tid] = sc;
        }
        __syncthreads();
        if (tid < 64) {
            float a = sh_sc[tid], c = sh_sc[tid + 64];
            float m = fmaxf(a, c);
            for (int off = 32; off; off >>= 1) m = fmaxf(m, __shfl_xor(m, off));
            float ea = __expf(a - m), ec = __expf(c - m);
            float ssum = ea + ec;
            for (int off = 32; off; off >>= 1) ssum += __shfl_xor(ssum, off);
            float inv = 1.f / ssum;
            sh_w[tid] = ea * inv;
            sh_w[tid + 64] = ec * inv;
            if (sl == 0) {
                float* ap = out_attn + ((size_t)(b * SS + s)) * TT;
                ap[tid] = ea * inv;
                ap[tid + 64] = ec * inv;
            }
        }
        __syncthreads();

        // ---- Phase 4: my 64 ctx rows (coalesced over i, split t across waves)
        {
            const float* ep = enc + ((size_t)b * TT + w * 32) * HH + 64 * sl + lane;
            float acc = 0.f;
#pragma unroll 8
            for (int t2 = 0; t2 < 32; t2++) acc += sh_w[w * 32 + t2] * ep[(size_t)t2 * HH];
            sh_cp[w][lane] = acc;
        }
        __syncthreads();
        if (tid < 64) sh_ctx[tid] = sh_cp[0][tid] + sh_cp[1][tid] + sh_cp[2][tid] + sh_cp[3][tid];
        __syncthreads();

        // ---- Phase 5: k-sliced gate partials for ALL 1536 rows
        {
            int sub = lane & 15, r4 = lane >> 4;
            float4 cx = *(const float4*)&sh_ctx[sub * 4];
            float4 hx = *(const float4*)&sh_h[64 * sl + sub * 4];
            const float* gie_row = gie + ((size_t)(b * SS + s)) * 1536;
#pragma unroll 4
            for (int it = 0; it < 96; it++) {
                int j = w * 384 + it * 4 + r4;
                const float4 wi = *(const float4*)(W_ih + (size_t)j * 1024 + 512 + 64 * sl + sub * 4);
                const float4 wh = *(const float4*)(W_hh + (size_t)j * 512 + 64 * sl + sub * 4);
                float gi = wi.x * cx.x + wi.y * cx.y + wi.z * cx.z + wi.w * cx.w;
                float gh = wh.x * hx.x + wh.y * hx.y + wh.z * hx.z + wh.w * hx.w;
#pragma unroll
                for (int off = 1; off < 16; off <<= 1) {
                    gi += __shfl_xor(gi, off);
                    gh += __shfl_xor(gh, off);
                }
                if (sub == 0) {
                    if (j < 1024) {
                        float v = gi + gh;
                        if (sl == 0) v += gie_row[j] + b_hh[j];
                        gp_b[j] = v;
                    } else {
                        float vi = gi, vh = gh;
                        if (sl == 0) { vi += gie_row[j]; vh += b_hh[j]; }
                        gp_b[j] = vi;          // gin region [1024,1536)
                        gp_b[j + 512] = vh;    // ghn region [1536,2048)
                    }
                }
            }
        }
        bc += NSL; group_bar(ctr, bc);   // gate partials published

        // ---- Phase 6: h update for my 64 indices
        if (tid < 64) {
            int i = 64 * sl + tid;
            float rp = 0.f, zp = 0.f, gin = 0.f, ghn = 0.f;
#pragma unroll
            for (int s2 = 0; s2 < NSL; s2++) {
                const float* g = gp + (size_t)(s2 * BB + b) * 2048;
                rp += g[i]; zp += g[512 + i]; gin += g[1024 + i]; ghn += g[1536 + i];
            }
            float r = sigmoid_fast(rp), z = sigmoid_fast(zp);
            float n = tanh_fast(gin + r * ghn);
            float hn = (1.f - z) * n + z * sh_h[i];
            hs[((size_t)(b * SS + s)) * HH + i] = hn;
            if (s == SS - 1) out_hT[b * HH + i] = hn;
        }
        bc += NSL; group_bar(ctr, bc);   // h published
    }
}

// ---------------------------------------------------------------------------
// In-place log_softmax over rows of 32000
__global__ __launch_bounds__(256) void lse_kernel(float* __restrict__ logits) {
    int row = blockIdx.x;
    float* rp = logits + (size_t)row * VV;
    int tid = threadIdx.x;
    __shared__ float red[4];
    __shared__ float bc;
    float m = -INFINITY;
    for (int i = tid; i < VV; i += 256) m = fmaxf(m, rp[i]);
    for (int off = 32; off; off >>= 1) m = fmaxf(m, __shfl_xor(m, off));
    if ((tid & 63) == 0) red[tid >> 6] = m;
    __syncthreads();
    if (tid == 0) bc = fmaxf(fmaxf(red[0], red[1]), fmaxf(red[2], red[3]));
    __syncthreads();
    m = bc;
    float ssum = 0.f;
    for (int i = tid; i < VV; i += 256) ssum += __expf(rp[i] - m);
    for (int off = 32; off; off >>= 1) ssum += __shfl_xor(ssum, off);
    if ((tid & 63) == 0) red[tid >> 6] = ssum;
    __syncthreads();
    if (tid == 0) bc = m + logf(red[0] + red[1] + red[2] + red[3]);
    __syncthreads();
    float lse = bc;
    for (int i = tid; i < VV; i += 256) rp[i] -= lse;
}

// ---------------------------------------------------------------------------
extern "C" void kernel_launch(void* const* d_in, const int* in_sizes, int n_in,
                              void* d_out, int out_size, void* d_ws, size_t ws_size,
                              hipStream_t stream) {
    const float* enc     = (const float*)d_in[0];
    const float* enc_hid = (const float*)d_in[1];
    const int*   tgt     = (const int*)d_in[2];
    const float* emb     = (const float*)d_in[3];
    const float* Wa_w    = (const float*)d_in[4];
    const float* Wa_b    = (const float*)d_in[5];
    const float* Ua_w    = (const float*)d_in[6];
    const float* Ua_b    = (const float*)d_in[7];
    const float* Va_w    = (const float*)d_in[8];
    const float* Va_b    = (const float*)d_in[9];
    const float* W_ih    = (const float*)d_in[10];
    const float* W_hh    = (const float*)d_in[11];
    const float* b_ih    = (const float*)d_in[12];
    const float* b_hh    = (const float*)d_in[13];
    const float* out_w   = (const float*)d_in[14];
    const float* out_b   = (const float*)d_in[15];
    float* out = (float*)d_out;

    float* ws      = (float*)d_ws;
    float* ws_emb  = ws;                          // 2048*512  (reused by recur scratch)
    float* ws_ua   = ws_emb + 2048 * 512;         // 4096*512
    float* ws_gie  = ws_ua + 4096 * 512;          // 2048*1536
    float* ws_hs   = ws_gie + 2048 * 1536;        // 2048*512
    // recur-time aliases of the (consumed) emb region:
    int*   ws_sync = (int*)ws;                    // 32 counters (first 64 ints)
    float* ws_scp  = ws + 64;                     // 8*32*128
    float* ws_gp   = ws + 64 + NSL * BB * TT;     // 8*32*2048

    float* out_logits = out;                                  // [B*S, V]
    float* out_hT     = out + (size_t)BB * SS * VV;           // [B, H]
    float* out_attn   = out_hT + (size_t)BB * HH;             // [B, S, T]

    gather_emb<<<dim3(2048), dim3(256), 0, stream>>>(tgt, emb, ws_emb);
    gemm_bias<<<dim3(8, 64), dim3(256), 0, stream>>>(
        enc, HH, Ua_w, HH, Ua_b, ws_ua, HH, HH);
    gemm_bias<<<dim3(24, 32), dim3(256), 0, stream>>>(
        ws_emb, HH, W_ih, 2 * HH, b_ih, ws_gie, 3 * HH, HH);
    // zero the barrier counters (after the gie GEMM consumed the emb region)
    hipMemsetAsync(d_ws, 0, 256, stream);
    recur2<<<dim3(BB * NSL), dim3(256), 0, stream>>>(
        enc, enc_hid, Wa_w, Wa_b, Va_w, Va_b, W_ih, W_hh, b_hh,
        ws_ua, ws_gie, ws_sync, ws_scp, ws_gp, ws_hs, out_hT, out_attn);
    gemm_bias<<<dim3(500, 32), dim3(256), 0, stream>>>(
        ws_hs, HH, out_w, HH, out_b, out_logits, VV, HH);
    lse_kernel<<<dim3(2048), dim3(256), 0, stream>>>(out_logits);
}